// Round 1
// baseline (290.655 us; speedup 1.0000x reference)
//
#include <hip/hip_runtime.h>
#include <math.h>

#define BATCH 32
#define CH    128
#define HW    4096   // 64*64

// ---------------------------------------------------------------------------
// Kernel 1: pooled[b*C+c] = mean over HW of condition[b,c,:,:]
// grid = B*C = 4096 blocks, 256 threads. Each block reduces 4096 floats.
// ---------------------------------------------------------------------------
__global__ __launch_bounds__(256) void pool_kernel(const float* __restrict__ cond,
                                                   float* __restrict__ pooled) {
    int bc = blockIdx.x;
    const float4* base = (const float4*)(cond + (size_t)bc * HW);
    int tid = threadIdx.x;
    float s = 0.f;
#pragma unroll
    for (int k = 0; k < 4; ++k) {
        float4 v = base[tid + k * 256];
        s += v.x + v.y + v.z + v.w;
    }
    for (int off = 32; off; off >>= 1) s += __shfl_down(s, off, 64);
    __shared__ float red[4];
    if ((tid & 63) == 0) red[tid >> 6] = s;
    __syncthreads();
    if (tid == 0) pooled[bc] = (red[0] + red[1] + red[2] + red[3]) * (1.0f / HW);
}

// ---------------------------------------------------------------------------
// Kernel 2: wmat[b][n] = dot(pooled[b][:], w_lin[n][:]) + b_lin[n] + (o==i)
//           n = o*C + i,  n in [0, C*C)
// grid = 64 blocks x 256 threads, one thread per n, all 32 batches per thread.
// ---------------------------------------------------------------------------
__global__ __launch_bounds__(256) void wmat_kernel(const float* __restrict__ pooled,
                                                   const float* __restrict__ w_lin,
                                                   const float* __restrict__ b_lin,
                                                   float* __restrict__ wmat) {
    __shared__ float4 pl[BATCH * CH / 4];   // pooled staged: pl[b*32 + k4]
    int tid = threadIdx.x;
    const float4* p4 = (const float4*)pooled;
    for (int idx = tid; idx < BATCH * CH / 4; idx += 256) pl[idx] = p4[idx];
    __syncthreads();

    int n = blockIdx.x * 256 + tid;
    const float4* row = (const float4*)(w_lin + (size_t)n * CH);
    float bl = b_lin[n];
    float acc[BATCH];
#pragma unroll
    for (int b = 0; b < BATCH; ++b) acc[b] = bl;

    for (int k4 = 0; k4 < CH / 4; ++k4) {
        float4 wv = row[k4];
#pragma unroll
        for (int b = 0; b < BATCH; ++b) {
            float4 pv = pl[b * 32 + k4];
            acc[b] += pv.x * wv.x + pv.y * wv.y + pv.z * wv.z + pv.w * wv.w;
        }
    }
    int o = n >> 7, i = n & 127;
    float diag = (o == i) ? 1.0f : 0.0f;
#pragma unroll
    for (int b = 0; b < BATCH; ++b)
        wmat[(size_t)b * (CH * CH) + n] = acc[b] + diag;
}

// ---------------------------------------------------------------------------
// Kernel 3: conv  out[b,o,p] = sum_i wmat[b,o,i] * inp[b,i,p]
// grid = (C/16 ochunks, HW/1024 tiles, B), 256 threads.
// Thread: 4 pixels (float4) x 16 output channels, K-loop over all 128 i.
// ---------------------------------------------------------------------------
#define OCH 16
__global__ __launch_bounds__(256) void conv_kernel(const float* __restrict__ inp,
                                                   const float* __restrict__ wmat,
                                                   float* __restrict__ out) {
    __shared__ float wlds[OCH * CH];   // 8 KB
    int och  = blockIdx.x;             // 0..7
    int tile = blockIdx.y;             // 0..3
    int b    = blockIdx.z;             // 0..31
    int tid  = threadIdx.x;

    const float* wsrc = wmat + ((size_t)b * CH + och * OCH) * CH;
    for (int idx = tid; idx < OCH * CH; idx += 256) wlds[idx] = wsrc[idx];
    __syncthreads();

    int pix = tile * 1024 + tid * 4;
    const float* ip = inp + (size_t)b * CH * HW + pix;

    float4 acc[OCH];
#pragma unroll
    for (int o = 0; o < OCH; ++o) acc[o] = make_float4(0.f, 0.f, 0.f, 0.f);

    for (int i4 = 0; i4 < CH / 4; ++i4) {
        float4 x0 = *(const float4*)(ip + (size_t)(i4 * 4 + 0) * HW);
        float4 x1 = *(const float4*)(ip + (size_t)(i4 * 4 + 1) * HW);
        float4 x2 = *(const float4*)(ip + (size_t)(i4 * 4 + 2) * HW);
        float4 x3 = *(const float4*)(ip + (size_t)(i4 * 4 + 3) * HW);
#pragma unroll
        for (int o = 0; o < OCH; ++o) {
            float4 wv = *(const float4*)&wlds[o * CH + i4 * 4];
            acc[o].x += wv.x * x0.x + wv.y * x1.x + wv.z * x2.x + wv.w * x3.x;
            acc[o].y += wv.x * x0.y + wv.y * x1.y + wv.z * x2.y + wv.w * x3.y;
            acc[o].z += wv.x * x0.z + wv.y * x1.z + wv.z * x2.z + wv.w * x3.z;
            acc[o].w += wv.x * x0.w + wv.y * x1.w + wv.z * x2.w + wv.w * x3.w;
        }
    }
    float* op = out + (size_t)b * CH * HW + pix;
#pragma unroll
    for (int o = 0; o < OCH; ++o)
        *(float4*)(op + (size_t)(och * OCH + o) * HW) = acc[o];
}

// ---------------------------------------------------------------------------
// Kernel 4: per-sample log|det| via unpivoted Gaussian elimination in LDS.
// W = I + E with ||E|| ~ 0.04, so no pivoting needed (diag ~ 1).
// LDS layout XOR-swizzled: word(i,j) = i*128 + ((j>>2)^((i>>3)&7))*4 + (j&3)
// so float4 row accesses across 64 lanes avoid >min bank serialization.
// grid = B blocks x 256 threads (thread = (row i, column-half h)).
// ---------------------------------------------------------------------------
__device__ __forceinline__ int swz(int i, int j) {
    return i * 128 + ((((j >> 2) ^ ((i >> 3) & 7)) << 2) | (j & 3));
}

__global__ __launch_bounds__(256) void logdet_kernel(const float* __restrict__ wmat,
                                                     float* __restrict__ partial) {
    __shared__ float A[CH * CH];   // 64 KB
    int bIdx = blockIdx.x;
    int tid  = threadIdx.x;

    const float4* src = (const float4*)(wmat + (size_t)bIdx * CH * CH);
    for (int idx = tid; idx < CH * CH / 4; idx += 256) {
        int r = idx >> 5;
        int q = idx & 31;
        float4 v = src[idx];
        int sq = q ^ ((r >> 3) & 7);
        *(float4*)&A[r * 128 + sq * 4] = v;
    }
    __syncthreads();

    int i   = tid & 127;
    int h   = tid >> 7;          // column-half: 0 or 1
    int isw = (i >> 3) & 7;

    for (int k = 0; k < CH - 1; ++k) {
        float piv = A[swz(k, k)];
        float mi = 0.f;
        if (i > k) mi = A[swz(i, k)] / piv;
        __syncthreads();                      // all m read before any write
        if (i > k) {
            int ksw = (k >> 3) & 7;
            int j4s = (k + 1) >> 2;           // may overlap cols <= k: harmless,
                                              // those columns are never re-read
            for (int j4 = j4s + h; j4 < 32; j4 += 2) {
                float4 pv = *(const float4*)&A[k * 128 + ((j4 ^ ksw) << 2)];
                float4 av = *(float4*)&A[i * 128 + ((j4 ^ isw) << 2)];
                av.x -= mi * pv.x; av.y -= mi * pv.y;
                av.z -= mi * pv.z; av.w -= mi * pv.w;
                *(float4*)&A[i * 128 + ((j4 ^ isw) << 2)] = av;
            }
        }
        __syncthreads();
    }

    float lg = 0.f;
    if (h == 0) lg = logf(fabsf(A[swz(i, i)]));
    for (int off = 32; off; off >>= 1) lg += __shfl_down(lg, off, 64);
    __shared__ float red[4];
    if ((tid & 63) == 0) red[tid >> 6] = lg;
    __syncthreads();
    if (tid == 0) partial[bIdx] = red[0] + red[1] + red[2] + red[3];
}

// ---------------------------------------------------------------------------
// Kernel 5: log_det = HW * mean_b(partial[b]) = sum * (4096/32) = sum * 128
// ---------------------------------------------------------------------------
__global__ void finalize_kernel(const float* __restrict__ partial,
                                float* __restrict__ out_scalar) {
    int tid = threadIdx.x;
    float v = (tid < BATCH) ? partial[tid] : 0.f;
    for (int off = 32; off; off >>= 1) v += __shfl_down(v, off, 64);
    if (tid == 0) out_scalar[0] = v * 128.0f;
}

// ---------------------------------------------------------------------------
extern "C" void kernel_launch(void* const* d_in, const int* in_sizes, int n_in,
                              void* d_out, int out_size, void* d_ws, size_t ws_size,
                              hipStream_t stream) {
    const float* inp   = (const float*)d_in[0];
    const float* cond  = (const float*)d_in[1];
    const float* w_lin = (const float*)d_in[2];
    const float* b_lin = (const float*)d_in[3];
    float* out = (float*)d_out;

    float* pooled  = (float*)d_ws;                       // 4096 floats
    float* wmat    = pooled + BATCH * CH;                // 524288 floats
    float* partial = wmat + BATCH * CH * CH;             // 32 floats

    pool_kernel<<<BATCH * CH, 256, 0, stream>>>(cond, pooled);
    wmat_kernel<<<CH * CH / 256, 256, 0, stream>>>(pooled, w_lin, b_lin, wmat);
    conv_kernel<<<dim3(CH / OCH, HW / 1024, BATCH), 256, 0, stream>>>(inp, wmat, out);
    logdet_kernel<<<BATCH, 256, 0, stream>>>(wmat, partial);
    finalize_kernel<<<1, 64, 0, stream>>>(partial, out + (size_t)BATCH * CH * HW);
}